// Round 8
// baseline (83205.365 us; speedup 1.0000x reference)
//
#include <hip/hip_runtime.h>
#include <cstddef>

#define T_LEN 131072

typedef float float2_t __attribute__((ext_vector_type(2)));
typedef float float4_t __attribute__((ext_vector_type(4)));

__device__ __forceinline__ float fast_sigmoid(float x) {
  float e = __builtin_amdgcn_exp2f(x * -1.44269504088896340736f);
  return __builtin_amdgcn_rcpf(1.0f + e);
}

__device__ __forceinline__ float fast_tanh(float x) {
  float e = __builtin_amdgcn_exp2f(x * 2.88539008177792681472f);
  return 1.0f - 2.0f * __builtin_amdgcn_rcpf(1.0f + e);
}

// ---------------------------------------------------------------------------
// Kernel A (parallel over T): hs_in = relu(x@W1+b1); gates[t] = hs_in @ {Wir,Wiz,Win} + b
// gates layout: [T][3][64] fp32
// ---------------------------------------------------------------------------
__global__ __launch_bounds__(256) void prep_kernel(
    const float* __restrict__ obs, const float* __restrict__ W1,
    const float* __restrict__ b1,
    const float* __restrict__ Wir, const float* __restrict__ bir,
    const float* __restrict__ Wiz, const float* __restrict__ biz,
    const float* __restrict__ Win, const float* __restrict__ bin,
    float* __restrict__ gates)
{
  __shared__ float sW1[36 * 64];
  __shared__ float sWg[3 * 4096];
  __shared__ float sb1[64];
  __shared__ float sbg[3 * 64];
  for (int i = threadIdx.x; i < 36 * 64; i += 256) sW1[i] = W1[i];
  for (int i = threadIdx.x; i < 4096; i += 256) {
    sWg[i] = Wir[i];
    sWg[4096 + i] = Wiz[i];
    sWg[8192 + i] = Win[i];
  }
  if (threadIdx.x < 64) {
    sb1[threadIdx.x] = b1[threadIdx.x];
    sbg[threadIdx.x] = bir[threadIdx.x];
    sbg[64 + threadIdx.x] = biz[threadIdx.x];
    sbg[128 + threadIdx.x] = bin[threadIdx.x];
  }
  __syncthreads();

  const int t = blockIdx.x * 256 + threadIdx.x;   // T divisible by 256

  float4_t x4[9];
  {
    const float4_t* op = (const float4_t*)(obs + (size_t)t * 36);
#pragma unroll
    for (int c = 0; c < 9; c++) x4[c] = op[c];
  }
  float4_t hacc[16];
  {
    const float4_t* bv = (const float4_t*)sb1;
#pragma unroll
    for (int k = 0; k < 16; k++) hacc[k] = bv[k];
  }
#pragma unroll
  for (int c = 0; c < 9; c++) {
#pragma unroll
    for (int q = 0; q < 4; q++) {
      const float xv = x4[c][q];
      const float4_t* wrow = (const float4_t*)(sW1 + (c * 4 + q) * 64);
#pragma unroll
      for (int k = 0; k < 16; k++) hacc[k] += xv * wrow[k];
    }
  }
#pragma unroll
  for (int k = 0; k < 16; k++) {
    hacc[k].x = fmaxf(hacc[k].x, 0.0f);
    hacc[k].y = fmaxf(hacc[k].y, 0.0f);
    hacc[k].z = fmaxf(hacc[k].z, 0.0f);
    hacc[k].w = fmaxf(hacc[k].w, 0.0f);
  }

  float* gout = gates + (size_t)t * 192;
  for (int g = 0; g < 3; g++) {   // rolled: caps register pressure
    const float* wg = sWg + g * 4096;
    float4_t acc[16];
    {
      const float4_t* bv = (const float4_t*)(sbg + g * 64);
#pragma unroll
      for (int k = 0; k < 16; k++) acc[k] = bv[k];
    }
#pragma unroll
    for (int ii = 0; ii < 16; ii++) {
      const float4_t hv4 = hacc[ii];
#pragma unroll
      for (int q = 0; q < 4; q++) {
        const float hv = hv4[q];
        const float4_t* wrow = (const float4_t*)(wg + (ii * 4 + q) * 64);
#pragma unroll
        for (int k = 0; k < 16; k++) acc[k] += hv * wrow[k];
      }
    }
    float4_t* outp = (float4_t*)(gout + g * 64);
#pragma unroll
    for (int k = 0; k < 16; k++) outp[k] = acc[k];
  }
}

// ---------------------------------------------------------------------------
// Kernel B (sequential): SINGLE wave, zero barriers, zero cross-wave traffic.
// R7 post-mortem: the 4-wave K-split's write->barrier->read exchange costs
// ~500 cyc/step (VALUBusy 0.149 x 256 = 38% per-CU => 310 issue / 820 total).
// Cross-wave sync is the wall, so: one wave, lane j owns output column j.
// - 96 float2 weight pairs (192 VGPRs) PINNED with volatile asm (R5/R6
//   proved volatile pinning holds values resident; R4's non-volatile didn't).
// - v_pk_fma_f32 via __builtin_elementwise_fma on float2: 96 packed FMAs =
//   192 issue cyc (fp32 peak 157 TF = 2x scalar rate, so pk is full-rate).
// - h broadcast: hbuf write -> ds_read_b128 uniform reads. Same-wave DS ops
//   execute in order; hbuf[j] store vs hb4[c] loads may-alias => compiler
//   keeps program order. NO s_barrier, NO asm memory clobber in the loop.
// - Numerics: identical accumulation order to R2 (passed, absmax 0.0078).
// ---------------------------------------------------------------------------
#define REP16(X) X(0) X(1) X(2) X(3) X(4) X(5) X(6) X(7) \
                 X(8) X(9) X(10) X(11) X(12) X(13) X(14) X(15)
#define REP8(X) X(0) X(1) X(2) X(3) X(4) X(5) X(6) X(7)

// weight pairs: chunk i covers k-elements 4i..4i+3; A = first pair, B = second
#define DECLW(i) float2_t wrA##i, wrB##i, wzA##i, wzB##i, wnA##i, wnB##i;

#define INITW(i) \
  wrA##i = float2_t{sW[(4*i)*64+j],        sW[(4*i+1)*64+j]}; \
  wrB##i = float2_t{sW[(4*i+2)*64+j],      sW[(4*i+3)*64+j]}; \
  wzA##i = float2_t{sW[4096+(4*i)*64+j],   sW[4096+(4*i+1)*64+j]}; \
  wzB##i = float2_t{sW[4096+(4*i+2)*64+j], sW[4096+(4*i+3)*64+j]}; \
  wnA##i = float2_t{sW[8192+(4*i)*64+j],   sW[8192+(4*i+1)*64+j]}; \
  wnB##i = float2_t{sW[8192+(4*i+2)*64+j], sW[8192+(4*i+3)*64+j]};

// volatile pin: opaque, non-sinkable defs -> weights stay in VGPRs
#define PINW(i) asm volatile("" : "+v"(wrA##i), "+v"(wrB##i), "+v"(wzA##i), \
                                  "+v"(wzB##i), "+v"(wnA##i), "+v"(wnB##i));

// one float4 chunk of the three matvecs: 6 v_pk_fma_f32
#define GSTEP(i) { \
  const float4_t hv = hb4[i];  /* ds_read_b128, uniform addr = broadcast */ \
  const float2_t hA = {hv.x, hv.y}, hB = {hv.z, hv.w}; \
  ar0 = __builtin_elementwise_fma(wrA##i, hA, ar0); \
  az0 = __builtin_elementwise_fma(wzA##i, hA, az0); \
  an0 = __builtin_elementwise_fma(wnA##i, hA, an0); \
  ar1 = __builtin_elementwise_fma(wrB##i, hB, ar1); \
  az1 = __builtin_elementwise_fma(wzB##i, hB, az1); \
  an1 = __builtin_elementwise_fma(wnB##i, hB, an1); }

#define DECLP(d) float pr##d, pz##d, pn##d;
#define PROLOAD(d) \
  pr##d = g0[(size_t)(d) * 192]; \
  pz##d = g0[(size_t)(d) * 192 + 64]; \
  pn##d = g0[(size_t)(d) * 192 + 128];

// one full GRU step, prefetch slot d. No asm, no barrier, no clobber.
#define STEP(d) { \
  const float xr = pr##d, xz = pz##d, xn = pn##d; \
  pr##d = gpf[0]; pz##d = gpf[64]; pn##d = gpf[128]; gpf += 192; \
  float2_t ar0 = {0.f,0.f}, ar1 = {0.f,0.f}; \
  float2_t az0 = {0.f,0.f}, az1 = {0.f,0.f}; \
  float2_t an0 = {0.f,0.f}, an1 = {0.f,0.f}; \
  REP16(GSTEP) \
  const float2_t ars = ar0 + ar1, azs = az0 + az1, ans = an0 + an1; \
  const float r = fast_sigmoid(xr + (ars.x + ars.y)); \
  const float z = fast_sigmoid(xz + (azs.x + azs.y)); \
  const float n = fast_tanh(xn + r * ((ans.x + ans.y) + bh)); \
  const float hn = n + z * (hprev - n);      /* (1-z)*n + z*h */ \
  hprev = hn; \
  *hp = hn; hp += 64;                        /* hs[t*64+j], store-only */ \
  hbuf[j] = hn;                              /* in-order DS pipe; next step's \
                                                hb4 reads may-alias => ordered */ \
}

__global__ __launch_bounds__(64, 1) void scan_kernel(
    const float* __restrict__ gates,
    const float* __restrict__ Whr, const float* __restrict__ Whz,
    const float* __restrict__ Whn, const float* __restrict__ bhn,
    float* __restrict__ hs)
{
  __shared__ float sW[3 * 4096];
  __shared__ __align__(16) float hbuf[64];
  const int j = threadIdx.x;

  // stage weights coalesced, then pull column j into named float2 registers
  for (int i = j; i < 4096; i += 64) {
    sW[i] = Whr[i];
    sW[4096 + i] = Whz[i];
    sW[8192 + i] = Whn[i];
  }
  __syncthreads();

  REP16(DECLW)
  REP16(INITW)
  REP16(PINW)
  float bh = bhn[j];
  asm volatile("" : "+v"(bh));

  float hprev = 0.0f;
  hbuf[j] = 0.0f;
  __syncthreads();

  // gate prefetch ring, distance 8 (use-waits hit ~8-step-old loads = free)
  REP8(DECLP)
  {
    const float* g0 = gates + j;
    REP8(PROLOAD)
  }
  const float* gpf = gates + j + (size_t)8 * 192;  // overruns 6KB into hs region: values discarded, safe
  float* hp = hs + j;
  const float4_t* hb4 = (const float4_t*)hbuf;

  for (int tb = 0; tb < T_LEN / 8; tb++) {
    STEP(0)
    STEP(1)
    STEP(2)
    STEP(3)
    STEP(4)
    STEP(5)
    STEP(6)
    STEP(7)
  }
}

// ---------------------------------------------------------------------------
// Kernel C (parallel over T): out[t][k] = hs[t] . Wend[:,perm[k]] + bend[perm[k]]
// perm = [1,0,3,2]
// ---------------------------------------------------------------------------
__global__ __launch_bounds__(256) void out_kernel(
    const float* __restrict__ hs, const float* __restrict__ Wend,
    const float* __restrict__ bend, float* __restrict__ out)
{
  __shared__ float4_t sWe[64];
  __shared__ float sbe[4];
  if (threadIdx.x < 64) sWe[threadIdx.x] = ((const float4_t*)Wend)[threadIdx.x];
  if (threadIdx.x < 4) sbe[threadIdx.x] = bend[threadIdx.x];
  __syncthreads();

  const int t = blockIdx.x * 256 + threadIdx.x;
  const float4_t* hp = (const float4_t*)(hs + (size_t)t * 64);
  float a0 = sbe[1], a1 = sbe[0], a2 = sbe[3], a3 = sbe[2];
#pragma unroll
  for (int c = 0; c < 16; c++) {
    const float4_t hv = hp[c];
#pragma unroll
    for (int q = 0; q < 4; q++) {
      const float hvq = hv[q];
      const float4_t w = sWe[c * 4 + q];   // Wend row, broadcast
      a0 += hvq * w.y;
      a1 += hvq * w.x;
      a2 += hvq * w.w;
      a3 += hvq * w.z;
    }
  }
  float4_t res = {a0, a1, a2, a3};
  ((float4_t*)out)[t] = res;
}

// ---------------------------------------------------------------------------
extern "C" void kernel_launch(void* const* d_in, const int* in_sizes, int n_in,
                              void* d_out, int out_size, void* d_ws, size_t ws_size,
                              hipStream_t stream) {
  (void)in_sizes; (void)n_in; (void)out_size; (void)ws_size;
  const float* obs  = (const float*)d_in[0];
  const float* W1   = (const float*)d_in[1];
  const float* b1   = (const float*)d_in[2];
  const float* Wir  = (const float*)d_in[3];
  const float* bir  = (const float*)d_in[4];
  const float* Wiz  = (const float*)d_in[5];
  const float* biz  = (const float*)d_in[6];
  const float* Win  = (const float*)d_in[7];
  const float* bin  = (const float*)d_in[8];
  const float* Whr  = (const float*)d_in[9];
  const float* Whz  = (const float*)d_in[10];
  const float* Whn  = (const float*)d_in[11];
  const float* bhn  = (const float*)d_in[12];
  const float* Wend = (const float*)d_in[13];
  const float* bend = (const float*)d_in[14];
  float* out = (float*)d_out;

  float* gates = (float*)d_ws;                    // [T,3,64] fp32 = 100.7 MB
  float* hs = gates + (size_t)T_LEN * 192;        // [T,64]   fp32 =  33.6 MB

  prep_kernel<<<T_LEN / 256, 256, 0, stream>>>(obs, W1, b1, Wir, bir, Wiz, biz,
                                               Win, bin, gates);
  scan_kernel<<<1, 64, 0, stream>>>(gates, Whr, Whz, Whn, bhn, hs);
  out_kernel<<<T_LEN / 256, 256, 0, stream>>>(hs, Wend, bend, out);
}

// Round 9
// 82437.830 us; speedup vs baseline: 1.0093x; 1.0093x over previous
//
#include <hip/hip_runtime.h>
#include <cstddef>

#define T_LEN 131072

typedef float float2_t __attribute__((ext_vector_type(2)));
typedef float float4_t __attribute__((ext_vector_type(4)));

__device__ __forceinline__ float fast_sigmoid(float x) {
  float e = __builtin_amdgcn_exp2f(x * -1.44269504088896340736f);
  return __builtin_amdgcn_rcpf(1.0f + e);
}

__device__ __forceinline__ float fast_tanh(float x) {
  float e = __builtin_amdgcn_exp2f(x * 2.88539008177792681472f);
  return 1.0f - 2.0f * __builtin_amdgcn_rcpf(1.0f + e);
}

// ---------------------------------------------------------------------------
// Kernel A (parallel over T): hs_in = relu(x@W1+b1); gates[t] = hs_in @ {Wir,Wiz,Win} + b
// gates layout: [T][3][64] fp32
// ---------------------------------------------------------------------------
__global__ __launch_bounds__(256) void prep_kernel(
    const float* __restrict__ obs, const float* __restrict__ W1,
    const float* __restrict__ b1,
    const float* __restrict__ Wir, const float* __restrict__ bir,
    const float* __restrict__ Wiz, const float* __restrict__ biz,
    const float* __restrict__ Win, const float* __restrict__ bin,
    float* __restrict__ gates)
{
  __shared__ float sW1[36 * 64];
  __shared__ float sWg[3 * 4096];
  __shared__ float sb1[64];
  __shared__ float sbg[3 * 64];
  for (int i = threadIdx.x; i < 36 * 64; i += 256) sW1[i] = W1[i];
  for (int i = threadIdx.x; i < 4096; i += 256) {
    sWg[i] = Wir[i];
    sWg[4096 + i] = Wiz[i];
    sWg[8192 + i] = Win[i];
  }
  if (threadIdx.x < 64) {
    sb1[threadIdx.x] = b1[threadIdx.x];
    sbg[threadIdx.x] = bir[threadIdx.x];
    sbg[64 + threadIdx.x] = biz[threadIdx.x];
    sbg[128 + threadIdx.x] = bin[threadIdx.x];
  }
  __syncthreads();

  const int t = blockIdx.x * 256 + threadIdx.x;   // T divisible by 256

  float4_t x4[9];
  {
    const float4_t* op = (const float4_t*)(obs + (size_t)t * 36);
#pragma unroll
    for (int c = 0; c < 9; c++) x4[c] = op[c];
  }
  float4_t hacc[16];
  {
    const float4_t* bv = (const float4_t*)sb1;
#pragma unroll
    for (int k = 0; k < 16; k++) hacc[k] = bv[k];
  }
#pragma unroll
  for (int c = 0; c < 9; c++) {
#pragma unroll
    for (int q = 0; q < 4; q++) {
      const float xv = x4[c][q];
      const float4_t* wrow = (const float4_t*)(sW1 + (c * 4 + q) * 64);
#pragma unroll
      for (int k = 0; k < 16; k++) hacc[k] += xv * wrow[k];
    }
  }
#pragma unroll
  for (int k = 0; k < 16; k++) {
    hacc[k].x = fmaxf(hacc[k].x, 0.0f);
    hacc[k].y = fmaxf(hacc[k].y, 0.0f);
    hacc[k].z = fmaxf(hacc[k].z, 0.0f);
    hacc[k].w = fmaxf(hacc[k].w, 0.0f);
  }

  float* gout = gates + (size_t)t * 192;
  for (int g = 0; g < 3; g++) {   // rolled: caps register pressure
    const float* wg = sWg + g * 4096;
    float4_t acc[16];
    {
      const float4_t* bv = (const float4_t*)(sbg + g * 64);
#pragma unroll
      for (int k = 0; k < 16; k++) acc[k] = bv[k];
    }
#pragma unroll
    for (int ii = 0; ii < 16; ii++) {
      const float4_t hv4 = hacc[ii];
#pragma unroll
      for (int q = 0; q < 4; q++) {
        const float hv = hv4[q];
        const float4_t* wrow = (const float4_t*)(wg + (ii * 4 + q) * 64);
#pragma unroll
        for (int k = 0; k < 16; k++) acc[k] += hv * wrow[k];
      }
    }
    float4_t* outp = (float4_t*)(gout + g * 64);
#pragma unroll
    for (int k = 0; k < 16; k++) outp[k] = acc[k];
  }
}

// ---------------------------------------------------------------------------
// Kernel B (sequential): SINGLE wave, barrier-free; R8 + amdgpu_waves_per_eu(1,1).
// R8 post-mortem: volatile pins blocked LDS-remat, but the allocator then
// SPILLED the weights to scratch (VGPR stuck at 136, 48KB scratch reload per
// step, ~1900 cyc/step). Conclusion: a VGPR budget of ~170 (512/3 waves-per-
// EU) is being enforced; __launch_bounds__(64,1)'s second arg did not lower
// it. Fix: explicit amdgpu_waves_per_eu(1,1) => budget 512 (256 arch) =>
// the ~240 VGPRs needed (96 float2 weights + working set) fit with neither
// remat nor spill. Everything else identical to R8.
// ---------------------------------------------------------------------------
#define REP16(X) X(0) X(1) X(2) X(3) X(4) X(5) X(6) X(7) \
                 X(8) X(9) X(10) X(11) X(12) X(13) X(14) X(15)
#define REP8(X) X(0) X(1) X(2) X(3) X(4) X(5) X(6) X(7)

// weight pairs: chunk i covers k-elements 4i..4i+3; A = first pair, B = second
#define DECLW(i) float2_t wrA##i, wrB##i, wzA##i, wzB##i, wnA##i, wnB##i;

#define INITW(i) \
  wrA##i = float2_t{sW[(4*i)*64+j],        sW[(4*i+1)*64+j]}; \
  wrB##i = float2_t{sW[(4*i+2)*64+j],      sW[(4*i+3)*64+j]}; \
  wzA##i = float2_t{sW[4096+(4*i)*64+j],   sW[4096+(4*i+1)*64+j]}; \
  wzB##i = float2_t{sW[4096+(4*i+2)*64+j], sW[4096+(4*i+3)*64+j]}; \
  wnA##i = float2_t{sW[8192+(4*i)*64+j],   sW[8192+(4*i+1)*64+j]}; \
  wnB##i = float2_t{sW[8192+(4*i+2)*64+j], sW[8192+(4*i+3)*64+j]};

// volatile pin: opaque, non-sinkable, non-rematerializable defs
#define PINW(i) asm volatile("" : "+v"(wrA##i), "+v"(wrB##i), "+v"(wzA##i), \
                                  "+v"(wzB##i), "+v"(wnA##i), "+v"(wnB##i));

// one float4 chunk of the three matvecs: 6 v_pk_fma_f32
#define GSTEP(i) { \
  const float4_t hv = hb4[i];  /* ds_read_b128, uniform addr = broadcast */ \
  const float2_t hA = {hv.x, hv.y}, hB = {hv.z, hv.w}; \
  ar0 = __builtin_elementwise_fma(wrA##i, hA, ar0); \
  az0 = __builtin_elementwise_fma(wzA##i, hA, az0); \
  an0 = __builtin_elementwise_fma(wnA##i, hA, an0); \
  ar1 = __builtin_elementwise_fma(wrB##i, hB, ar1); \
  az1 = __builtin_elementwise_fma(wzB##i, hB, az1); \
  an1 = __builtin_elementwise_fma(wnB##i, hB, an1); }

#define DECLP(d) float pr##d, pz##d, pn##d;
#define PROLOAD(d) \
  pr##d = g0[(size_t)(d) * 192]; \
  pz##d = g0[(size_t)(d) * 192 + 64]; \
  pn##d = g0[(size_t)(d) * 192 + 128];

// one full GRU step, prefetch slot d. No asm, no barrier, no clobber.
#define STEP(d) { \
  const float xr = pr##d, xz = pz##d, xn = pn##d; \
  pr##d = gpf[0]; pz##d = gpf[64]; pn##d = gpf[128]; gpf += 192; \
  float2_t ar0 = {0.f,0.f}, ar1 = {0.f,0.f}; \
  float2_t az0 = {0.f,0.f}, az1 = {0.f,0.f}; \
  float2_t an0 = {0.f,0.f}, an1 = {0.f,0.f}; \
  REP16(GSTEP) \
  const float2_t ars = ar0 + ar1, azs = az0 + az1, ans = an0 + an1; \
  const float r = fast_sigmoid(xr + (ars.x + ars.y)); \
  const float z = fast_sigmoid(xz + (azs.x + azs.y)); \
  const float n = fast_tanh(xn + r * ((ans.x + ans.y) + bh)); \
  const float hn = n + z * (hprev - n);      /* (1-z)*n + z*h */ \
  hprev = hn; \
  *hp = hn; hp += 64;                        /* hs[t*64+j], store-only */ \
  hbuf[j] = hn;                              /* in-order DS pipe; next step's \
                                                hb4 reads may-alias => ordered */ \
}

__global__ __launch_bounds__(64)
__attribute__((amdgpu_waves_per_eu(1, 1)))
void scan_kernel(
    const float* __restrict__ gates,
    const float* __restrict__ Whr, const float* __restrict__ Whz,
    const float* __restrict__ Whn, const float* __restrict__ bhn,
    float* __restrict__ hs)
{
  __shared__ float sW[3 * 4096];
  __shared__ __align__(16) float hbuf[64];
  const int j = threadIdx.x;

  // stage weights coalesced, then pull column j into named float2 registers
  for (int i = j; i < 4096; i += 64) {
    sW[i] = Whr[i];
    sW[4096 + i] = Whz[i];
    sW[8192 + i] = Whn[i];
  }
  __syncthreads();

  REP16(DECLW)
  REP16(INITW)
  REP16(PINW)
  float bh = bhn[j];
  asm volatile("" : "+v"(bh));

  float hprev = 0.0f;
  hbuf[j] = 0.0f;
  __syncthreads();

  // gate prefetch ring, distance 8 (use-waits hit ~8-step-old loads = free)
  REP8(DECLP)
  {
    const float* g0 = gates + j;
    REP8(PROLOAD)
  }
  const float* gpf = gates + j + (size_t)8 * 192;  // overruns 6KB into hs region: values discarded, safe
  float* hp = hs + j;
  const float4_t* hb4 = (const float4_t*)hbuf;

  for (int tb = 0; tb < T_LEN / 8; tb++) {
    STEP(0)
    STEP(1)
    STEP(2)
    STEP(3)
    STEP(4)
    STEP(5)
    STEP(6)
    STEP(7)
  }
}

// ---------------------------------------------------------------------------
// Kernel C (parallel over T): out[t][k] = hs[t] . Wend[:,perm[k]] + bend[perm[k]]
// perm = [1,0,3,2]
// ---------------------------------------------------------------------------
__global__ __launch_bounds__(256) void out_kernel(
    const float* __restrict__ hs, const float* __restrict__ Wend,
    const float* __restrict__ bend, float* __restrict__ out)
{
  __shared__ float4_t sWe[64];
  __shared__ float sbe[4];
  if (threadIdx.x < 64) sWe[threadIdx.x] = ((const float4_t*)Wend)[threadIdx.x];
  if (threadIdx.x < 4) sbe[threadIdx.x] = bend[threadIdx.x];
  __syncthreads();

  const int t = blockIdx.x * 256 + threadIdx.x;
  const float4_t* hp = (const float4_t*)(hs + (size_t)t * 64);
  float a0 = sbe[1], a1 = sbe[0], a2 = sbe[3], a3 = sbe[2];
#pragma unroll
  for (int c = 0; c < 16; c++) {
    const float4_t hv = hp[c];
#pragma unroll
    for (int q = 0; q < 4; q++) {
      const float hvq = hv[q];
      const float4_t w = sWe[c * 4 + q];   // Wend row, broadcast
      a0 += hvq * w.y;
      a1 += hvq * w.x;
      a2 += hvq * w.w;
      a3 += hvq * w.z;
    }
  }
  float4_t res = {a0, a1, a2, a3};
  ((float4_t*)out)[t] = res;
}

// ---------------------------------------------------------------------------
extern "C" void kernel_launch(void* const* d_in, const int* in_sizes, int n_in,
                              void* d_out, int out_size, void* d_ws, size_t ws_size,
                              hipStream_t stream) {
  (void)in_sizes; (void)n_in; (void)out_size; (void)ws_size;
  const float* obs  = (const float*)d_in[0];
  const float* W1   = (const float*)d_in[1];
  const float* b1   = (const float*)d_in[2];
  const float* Wir  = (const float*)d_in[3];
  const float* bir  = (const float*)d_in[4];
  const float* Wiz  = (const float*)d_in[5];
  const float* biz  = (const float*)d_in[6];
  const float* Win  = (const float*)d_in[7];
  const float* bin  = (const float*)d_in[8];
  const float* Whr  = (const float*)d_in[9];
  const float* Whz  = (const float*)d_in[10];
  const float* Whn  = (const float*)d_in[11];
  const float* bhn  = (const float*)d_in[12];
  const float* Wend = (const float*)d_in[13];
  const float* bend = (const float*)d_in[14];
  float* out = (float*)d_out;

  float* gates = (float*)d_ws;                    // [T,3,64] fp32 = 100.7 MB
  float* hs = gates + (size_t)T_LEN * 192;        // [T,64]   fp32 =  33.6 MB

  prep_kernel<<<T_LEN / 256, 256, 0, stream>>>(obs, W1, b1, Wir, bir, Wiz, biz,
                                               Win, bin, gates);
  scan_kernel<<<1, 64, 0, stream>>>(gates, Whr, Whz, Whn, bhn, hs);
  out_kernel<<<T_LEN / 256, 256, 0, stream>>>(hs, Wend, bend, out);
}

// Round 10
// 46123.990 us; speedup vs baseline: 1.8039x; 1.7873x over previous
//
#include <hip/hip_runtime.h>
#include <cstddef>

#define T_LEN 131072

typedef float float2_t __attribute__((ext_vector_type(2)));
typedef float float4_t __attribute__((ext_vector_type(4)));

__device__ __forceinline__ float fast_sigmoid(float x) {
  float e = __builtin_amdgcn_exp2f(x * -1.44269504088896340736f);
  return __builtin_amdgcn_rcpf(1.0f + e);
}

__device__ __forceinline__ float fast_tanh(float x) {
  float e = __builtin_amdgcn_exp2f(x * 2.88539008177792681472f);
  return 1.0f - 2.0f * __builtin_amdgcn_rcpf(1.0f + e);
}

// ---------------------------------------------------------------------------
// Kernel A (parallel over T): hs_in = relu(x@W1+b1); gates[t] = hs_in @ {Wir,Wiz,Win} + b
// gates layout: [T][3][64] fp32
// ---------------------------------------------------------------------------
__global__ __launch_bounds__(256) void prep_kernel(
    const float* __restrict__ obs, const float* __restrict__ W1,
    const float* __restrict__ b1,
    const float* __restrict__ Wir, const float* __restrict__ bir,
    const float* __restrict__ Wiz, const float* __restrict__ biz,
    const float* __restrict__ Win, const float* __restrict__ bin,
    float* __restrict__ gates)
{
  __shared__ float sW1[36 * 64];
  __shared__ float sWg[3 * 4096];
  __shared__ float sb1[64];
  __shared__ float sbg[3 * 64];
  for (int i = threadIdx.x; i < 36 * 64; i += 256) sW1[i] = W1[i];
  for (int i = threadIdx.x; i < 4096; i += 256) {
    sWg[i] = Wir[i];
    sWg[4096 + i] = Wiz[i];
    sWg[8192 + i] = Win[i];
  }
  if (threadIdx.x < 64) {
    sb1[threadIdx.x] = b1[threadIdx.x];
    sbg[threadIdx.x] = bir[threadIdx.x];
    sbg[64 + threadIdx.x] = biz[threadIdx.x];
    sbg[128 + threadIdx.x] = bin[threadIdx.x];
  }
  __syncthreads();

  const int t = blockIdx.x * 256 + threadIdx.x;   // T divisible by 256

  float4_t x4[9];
  {
    const float4_t* op = (const float4_t*)(obs + (size_t)t * 36);
#pragma unroll
    for (int c = 0; c < 9; c++) x4[c] = op[c];
  }
  float4_t hacc[16];
  {
    const float4_t* bv = (const float4_t*)sb1;
#pragma unroll
    for (int k = 0; k < 16; k++) hacc[k] = bv[k];
  }
#pragma unroll
  for (int c = 0; c < 9; c++) {
#pragma unroll
    for (int q = 0; q < 4; q++) {
      const float xv = x4[c][q];
      const float4_t* wrow = (const float4_t*)(sW1 + (c * 4 + q) * 64);
#pragma unroll
      for (int k = 0; k < 16; k++) hacc[k] += xv * wrow[k];
    }
  }
#pragma unroll
  for (int k = 0; k < 16; k++) {
    hacc[k].x = fmaxf(hacc[k].x, 0.0f);
    hacc[k].y = fmaxf(hacc[k].y, 0.0f);
    hacc[k].z = fmaxf(hacc[k].z, 0.0f);
    hacc[k].w = fmaxf(hacc[k].w, 0.0f);
  }

  float* gout = gates + (size_t)t * 192;
  for (int g = 0; g < 3; g++) {   // rolled: caps register pressure
    const float* wg = sWg + g * 4096;
    float4_t acc[16];
    {
      const float4_t* bv = (const float4_t*)(sbg + g * 64);
#pragma unroll
      for (int k = 0; k < 16; k++) acc[k] = bv[k];
    }
#pragma unroll
    for (int ii = 0; ii < 16; ii++) {
      const float4_t hv4 = hacc[ii];
#pragma unroll
      for (int q = 0; q < 4; q++) {
        const float hv = hv4[q];
        const float4_t* wrow = (const float4_t*)(wg + (ii * 4 + q) * 64);
#pragma unroll
        for (int k = 0; k < 16; k++) acc[k] += hv * wrow[k];
      }
    }
    float4_t* outp = (float4_t*)(gout + g * 64);
#pragma unroll
    for (int k = 0; k < 16; k++) outp[k] = acc[k];
  }
}

// ---------------------------------------------------------------------------
// Kernel B (sequential): single wave, HYBRID weight residency.
// R9 post-mortem: the allocator hard-caps this kernel at ~136 VGPRs — both
// __launch_bounds__(64,1) and amdgpu_waves_per_eu(1,1) were ignored; full
// register residency (192 weight VGPRs) is unreachable (spill: R8/R9 at
// ~1900 cyc/step; remat: R2-R4 at ~850). Design under the cap instead:
//  - k=0..23 (x3 gates) = 72 floats PINNED in VGPRs (fits: 72+~50 < 136;
//    pins are anti-remat per R8, and no spill motive below the cap).
//  - k=24..63 streamed per step from LDS as 30 ds_read_b128 from a
//    [chunk][lane] float4 layout (canonical conflict-free pattern).
//  - h broadcast via hbuf (separate LDS object from sWs => no alias =>
//    scheduler may hoist next step's weight reads over the hbuf write,
//    filling the serial tail with LDS work).
// Cycle model: LDS 30*12 + 16*(6-12) = 456-552, VALU ~270 overlapped,
// serial ~100 => ~550-650 cyc/step => 30-36 ms.
// ---------------------------------------------------------------------------
#define REP4(X) X(0) X(1) X(2) X(3)
#define REP6(X) X(0) X(1) X(2) X(3) X(4) X(5)
#define REP10(X) X(0) X(1) X(2) X(3) X(4) X(5) X(6) X(7) X(8) X(9)

// register weights: chunk i covers k=4i..4i+3 (i=0..5), A/B = float2 halves
#define DECLW(i) float2_t wrA##i, wrB##i, wzA##i, wzB##i, wnA##i, wnB##i;
#define INITW(i) \
  wrA##i = float2_t{Whr[(4*i)*64+j],   Whr[(4*i+1)*64+j]}; \
  wrB##i = float2_t{Whr[(4*i+2)*64+j], Whr[(4*i+3)*64+j]}; \
  wzA##i = float2_t{Whz[(4*i)*64+j],   Whz[(4*i+1)*64+j]}; \
  wzB##i = float2_t{Whz[(4*i+2)*64+j], Whz[(4*i+3)*64+j]}; \
  wnA##i = float2_t{Whn[(4*i)*64+j],   Whn[(4*i+1)*64+j]}; \
  wnB##i = float2_t{Whn[(4*i+2)*64+j], Whn[(4*i+3)*64+j]};
#define PINW(i) asm volatile("" : "+v"(wrA##i), "+v"(wrB##i), "+v"(wzA##i), \
                                  "+v"(wzB##i), "+v"(wnA##i), "+v"(wnB##i));

// register-resident chunk: 6 v_pk_fma_f32
#define RSTEP(i) { \
  const float4_t hv = hb4[i];  /* uniform ds_read_b128 = broadcast */ \
  const float2_t hA = {hv.x, hv.y}, hB = {hv.z, hv.w}; \
  ar0 = __builtin_elementwise_fma(wrA##i, hA, ar0); \
  az0 = __builtin_elementwise_fma(wzA##i, hA, az0); \
  an0 = __builtin_elementwise_fma(wnA##i, hA, an0); \
  ar1 = __builtin_elementwise_fma(wrB##i, hB, ar1); \
  az1 = __builtin_elementwise_fma(wzB##i, hB, az1); \
  an1 = __builtin_elementwise_fma(wnB##i, hB, an1); }

// streamed chunk cc (k=24+4cc): 3 ds_read_b128 + 6 v_pk_fma_f32
#define SSTEP(cc) { \
  const float4_t hv = hb4[6 + (cc)]; \
  const float2_t hA = {hv.x, hv.y}, hB = {hv.z, hv.w}; \
  const float4_t wrv = sWs[((cc)*3 + 0)*64 + j]; \
  const float4_t wzv = sWs[((cc)*3 + 1)*64 + j]; \
  const float4_t wnv = sWs[((cc)*3 + 2)*64 + j]; \
  ar0 = __builtin_elementwise_fma(float2_t{wrv.x, wrv.y}, hA, ar0); \
  ar1 = __builtin_elementwise_fma(float2_t{wrv.z, wrv.w}, hB, ar1); \
  az0 = __builtin_elementwise_fma(float2_t{wzv.x, wzv.y}, hA, az0); \
  az1 = __builtin_elementwise_fma(float2_t{wzv.z, wzv.w}, hB, az1); \
  an0 = __builtin_elementwise_fma(float2_t{wnv.x, wnv.y}, hA, an0); \
  an1 = __builtin_elementwise_fma(float2_t{wnv.z, wnv.w}, hB, an1); }

#define DECLP(d) float pr##d, pz##d, pn##d;
#define PROLOAD(d) \
  pr##d = g0[(size_t)(d) * 192]; \
  pz##d = g0[(size_t)(d) * 192 + 64]; \
  pn##d = g0[(size_t)(d) * 192 + 128];

// one full GRU step, prefetch slot d. No asm, no barrier, no clobber.
#define STEP(d) { \
  const float xr = pr##d, xz = pz##d, xn = pn##d; \
  pr##d = gpf[0]; pz##d = gpf[64]; pn##d = gpf[128]; gpf += 192; \
  float2_t ar0 = {0.f,0.f}, ar1 = {0.f,0.f}; \
  float2_t az0 = {0.f,0.f}, az1 = {0.f,0.f}; \
  float2_t an0 = {0.f,0.f}, an1 = {0.f,0.f}; \
  REP6(RSTEP) \
  REP10(SSTEP) \
  const float2_t ars = ar0 + ar1, azs = az0 + az1, ans = an0 + an1; \
  const float r = fast_sigmoid(xr + (ars.x + ars.y)); \
  const float z = fast_sigmoid(xz + (azs.x + azs.y)); \
  const float n = fast_tanh(xn + r * ((ans.x + ans.y) + bh)); \
  const float hn = n + z * (hprev - n);      /* (1-z)*n + z*h */ \
  hprev = hn; \
  *hp = hn; hp += 64;                        /* hs[t*64+j], store-only */ \
  hbuf[j] = hn;                              /* in-order DS pipe; next step's \
                                                hb4 reads may-alias => ordered */ \
}

__global__ __launch_bounds__(64) void scan_kernel(
    const float* __restrict__ gates,
    const float* __restrict__ Whr, const float* __restrict__ Whz,
    const float* __restrict__ Whn, const float* __restrict__ bhn,
    float* __restrict__ hs)
{
  __shared__ float4_t sWs[30 * 64];             // 30 KB streamed weights, [chunk][lane]
  __shared__ __align__(16) float hbuf[64];      // separate object: no alias with sWs
  const int j = threadIdx.x;

  // build streamed layout: chunk cc covers k=24+4cc, per gate, lane-major
  for (int cc = 0; cc < 10; cc++) {
    const int k0 = 24 + 4 * cc;
    sWs[(cc*3 + 0)*64 + j] = float4_t{Whr[(k0)*64+j], Whr[(k0+1)*64+j],
                                      Whr[(k0+2)*64+j], Whr[(k0+3)*64+j]};
    sWs[(cc*3 + 1)*64 + j] = float4_t{Whz[(k0)*64+j], Whz[(k0+1)*64+j],
                                      Whz[(k0+2)*64+j], Whz[(k0+3)*64+j]};
    sWs[(cc*3 + 2)*64 + j] = float4_t{Whn[(k0)*64+j], Whn[(k0+1)*64+j],
                                      Whn[(k0+2)*64+j], Whn[(k0+3)*64+j]};
  }

  REP6(DECLW)
  REP6(INITW)
  REP6(PINW)
  float bh = bhn[j];
  asm volatile("" : "+v"(bh));

  float hprev = 0.0f;
  hbuf[j] = 0.0f;
  __syncthreads();

  // gate prefetch ring, distance 4
  REP4(DECLP)
  {
    const float* g0 = gates + j;
    REP4(PROLOAD)
  }
  const float* gpf = gates + j + (size_t)4 * 192;  // overruns 3KB into hs region: values discarded, safe
  float* hp = hs + j;
  const float4_t* hb4 = (const float4_t*)hbuf;

  for (int tb = 0; tb < T_LEN / 4; tb++) {
    STEP(0)
    STEP(1)
    STEP(2)
    STEP(3)
  }
}

// ---------------------------------------------------------------------------
// Kernel C (parallel over T): out[t][k] = hs[t] . Wend[:,perm[k]] + bend[perm[k]]
// perm = [1,0,3,2]
// ---------------------------------------------------------------------------
__global__ __launch_bounds__(256) void out_kernel(
    const float* __restrict__ hs, const float* __restrict__ Wend,
    const float* __restrict__ bend, float* __restrict__ out)
{
  __shared__ float4_t sWe[64];
  __shared__ float sbe[4];
  if (threadIdx.x < 64) sWe[threadIdx.x] = ((const float4_t*)Wend)[threadIdx.x];
  if (threadIdx.x < 4) sbe[threadIdx.x] = bend[threadIdx.x];
  __syncthreads();

  const int t = blockIdx.x * 256 + threadIdx.x;
  const float4_t* hp = (const float4_t*)(hs + (size_t)t * 64);
  float a0 = sbe[1], a1 = sbe[0], a2 = sbe[3], a3 = sbe[2];
#pragma unroll
  for (int c = 0; c < 16; c++) {
    const float4_t hv = hp[c];
#pragma unroll
    for (int q = 0; q < 4; q++) {
      const float hvq = hv[q];
      const float4_t w = sWe[c * 4 + q];   // Wend row, broadcast
      a0 += hvq * w.y;
      a1 += hvq * w.x;
      a2 += hvq * w.w;
      a3 += hvq * w.z;
    }
  }
  float4_t res = {a0, a1, a2, a3};
  ((float4_t*)out)[t] = res;
}

// ---------------------------------------------------------------------------
extern "C" void kernel_launch(void* const* d_in, const int* in_sizes, int n_in,
                              void* d_out, int out_size, void* d_ws, size_t ws_size,
                              hipStream_t stream) {
  (void)in_sizes; (void)n_in; (void)out_size; (void)ws_size;
  const float* obs  = (const float*)d_in[0];
  const float* W1   = (const float*)d_in[1];
  const float* b1   = (const float*)d_in[2];
  const float* Wir  = (const float*)d_in[3];
  const float* bir  = (const float*)d_in[4];
  const float* Wiz  = (const float*)d_in[5];
  const float* biz  = (const float*)d_in[6];
  const float* Win  = (const float*)d_in[7];
  const float* bin  = (const float*)d_in[8];
  const float* Whr  = (const float*)d_in[9];
  const float* Whz  = (const float*)d_in[10];
  const float* Whn  = (const float*)d_in[11];
  const float* bhn  = (const float*)d_in[12];
  const float* Wend = (const float*)d_in[13];
  const float* bend = (const float*)d_in[14];
  float* out = (float*)d_out;

  float* gates = (float*)d_ws;                    // [T,3,64] fp32 = 100.7 MB
  float* hs = gates + (size_t)T_LEN * 192;        // [T,64]   fp32 =  33.6 MB

  prep_kernel<<<T_LEN / 256, 256, 0, stream>>>(obs, W1, b1, Wir, bir, Wiz, biz,
                                               Win, bin, gates);
  scan_kernel<<<1, 64, 0, stream>>>(gates, Whr, Whz, Whn, bhn, hs);
  out_kernel<<<T_LEN / 256, 256, 0, stream>>>(hs, Wend, bend, out);
}